// Round 8
// baseline (61.540 us; speedup 1.0000x reference)
//
#include <hip/hip_runtime.h>

#define NT 320            // 4 compute waves + 1 storer wave
#define NSTEP 50
#define PSTR 17           // LDS dwords per particle per slot (max 15 used + 2)
#define SLOTW (64 * PSTR) // dwords per slot
#define NCH 6

// chunk schedule (entries): small head chunk -> flushing starts early;
// small tail chunk -> short exposed final drain. All even.
__device__ __constant__ const int kLen[NCH] = {4, 10, 10, 10, 10, 6};
// e0dw = 3 * cumulative entries
__device__ __constant__ const int kOff[NCH] = {0, 12, 42, 72, 102, 132};

__device__ __forceinline__ void lorenz(float x, float y, float z,
                                       float S, float R, float Bb,
                                       float c0, float c1, float c2,
                                       float& dx, float& dy, float& dz) {
    dx = S * (y - x) + c0;
    dy = x * (R - z) - y + c1;
    dz = x * y - Bb * z + c2;
}

__device__ __forceinline__ unsigned int bpack(float lo, float hi) {
    unsigned int a = (__builtin_bit_cast(unsigned int, lo) + 0x8000u) >> 16;
    unsigned int b = (__builtin_bit_cast(unsigned int, hi) + 0x8000u) & 0xFFFF0000u;
    return a | b;
}
__device__ __forceinline__ float bunpack_lo(unsigned int w) {
    return __builtin_bit_cast(float, w << 16);
}
__device__ __forceinline__ float bunpack_hi(unsigned int w) {
    return __builtin_bit_cast(float, w & 0xFFFF0000u);
}

__device__ __forceinline__ float tanh_fast(float x) {
    float e = __expf(2.0f * x);
    float r = __builtin_amdgcn_rcpf(e + 1.0f);
    return __builtin_fmaf(-2.0f, r, 1.0f);
}
__device__ __forceinline__ float sigmoid_fast(float x) {
    float e = __expf(-x);
    return __builtin_amdgcn_rcpf(1.0f + e);
}

// bounded spin on an LDS flag (uniform across wave). Bounded so a sync bug
// fails the bench visibly instead of hanging it.
__device__ __forceinline__ void waitGE(const int* f, int v) {
    int guard = 0;
    while (*(const volatile int*)f < v) {
        __builtin_amdgcn_s_sleep(2);
        if (++guard > (1 << 20)) break;
    }
}

// flush one chunk image: CNT packed dwords per particle, 64 particles.
// lane covers dword i = 64k+lane; out = 2 f32 per dword, 8B-aligned.
template<int CNT>
__device__ __forceinline__ void flushChunkT(const unsigned int* __restrict__ fb,
                                            float* __restrict__ outW,
                                            int lane, int e0dw) {
    #pragma unroll
    for (int k = 0; k < CNT; ++k) {
        const int i  = 64 * k + lane;
        const int pp = i / CNT;            // const divisor -> magic mul
        const int j  = i - pp * CNT;
        const unsigned int v = fb[pp * PSTR + j];
        float2 o;
        o.x = bunpack_lo(v);
        o.y = bunpack_hi(v);
        *(float2*)(outW + pp * 150 + e0dw + 2 * j) = o;
    }
}

__global__ __launch_bounds__(NT) void chaotic_embed_kernel(
    const float* __restrict__ features,
    const float* __restrict__ W1,  const float* __restrict__ b1,
    const float* __restrict__ W2,  const float* __restrict__ b2,
    const float* __restrict__ Wc1, const float* __restrict__ bc1,
    const float* __restrict__ Wc2, const float* __restrict__ bc2,
    const float* __restrict__ Wp1, const float* __restrict__ bp1,
    const float* __restrict__ Wp2, const float* __restrict__ bp2,
    float* __restrict__ out)
{
    __shared__ unsigned int stage[4 * 2 * SLOTW];  // [wave][slot][64*PSTR]
    __shared__ int ready[4];   // chunks published by compute wave w
    __shared__ int freed[4];   // chunks flushed by storer for wave w

    const int tid  = threadIdx.x;
    const int wv   = tid >> 6;          // 0..3 compute, 4 storer
    const int lane = tid & 63;

    if (tid < 4) { ready[tid] = 0; freed[tid] = 0; }
    __syncthreads();

    const long blockBase = (long)blockIdx.x * 256;

    if (wv < 4) {
        // ================= COMPUTE WAVE =================
        const long p = blockBase + (long)wv * 64 + lane;
        const float4 f4 = ((const float4*)features)[p];
        const float fv[4] = {f4.x, f4.y, f4.z, f4.w};

        // MLPs (uniform s_load weights, SGPR operands)
        float h1[16];
        #pragma unroll
        for (int j = 0; j < 16; ++j) {
            float a = b1[j];
            #pragma unroll
            for (int i = 0; i < 4; ++i) a = __builtin_fmaf(fv[i], W1[i * 16 + j], a);
            h1[j] = tanh_fast(a);
        }
        float init[3];
        #pragma unroll
        for (int c = 0; c < 3; ++c) {
            float a = b2[c];
            #pragma unroll
            for (int j = 0; j < 16; ++j) a = __builtin_fmaf(h1[j], W2[j * 3 + c], a);
            init[c] = 2.0f * tanh_fast(a);
        }
        float hc[8];
        #pragma unroll
        for (int j = 0; j < 8; ++j) {
            float a = bc1[j];
            #pragma unroll
            for (int i = 0; i < 4; ++i) a = __builtin_fmaf(fv[i], Wc1[i * 8 + j], a);
            hc[j] = tanh_fast(a);
        }
        float coup[3];
        #pragma unroll
        for (int c = 0; c < 3; ++c) {
            float a = bc2[c];
            #pragma unroll
            for (int j = 0; j < 8; ++j) a = __builtin_fmaf(hc[j], Wc2[j * 3 + c], a);
            coup[c] = tanh_fast(a);
        }
        float hp[8];
        #pragma unroll
        for (int j = 0; j < 8; ++j) {
            float a = bp1[j];
            #pragma unroll
            for (int i = 0; i < 4; ++i) a = __builtin_fmaf(fv[i], Wp1[i * 8 + j], a);
            hp[j] = fmaxf(a, 0.0f);
        }
        float sc[3];
        #pragma unroll
        for (int c = 0; c < 3; ++c) {
            float a = bp2[c];
            #pragma unroll
            for (int j = 0; j < 8; ++j) a = __builtin_fmaf(hp[j], Wp2[j * 3 + c], a);
            sc[c] = sigmoid_fast(a);
        }
        const float S  = 10.0f * (0.5f + sc[0]);
        const float R  = 28.0f * (0.5f + sc[1]);
        const float Bb = (8.0f / 3.0f) * (0.5f + sc[2]);
        const float c0 = coup[0], c1 = coup[1], c2 = coup[2];
        const float H = 0.01f, HH = 0.5f * 0.01f, H6 = 0.01f / 6.0f;

        float sx = init[0], sy = init[1], sz = init[2];
        float px, py, pz;

        auto step = [&]() {
            float k1x, k1y, k1z, k2x, k2y, k2z, k3x, k3y, k3z, k4x, k4y, k4z;
            lorenz(sx, sy, sz, S, R, Bb, c0, c1, c2, k1x, k1y, k1z);
            lorenz(sx + HH * k1x, sy + HH * k1y, sz + HH * k1z,
                   S, R, Bb, c0, c1, c2, k2x, k2y, k2z);
            lorenz(sx + HH * k2x, sy + HH * k2y, sz + HH * k2z,
                   S, R, Bb, c0, c1, c2, k3x, k3y, k3z);
            lorenz(sx + H * k3x, sy + H * k3y, sz + H * k3z,
                   S, R, Bb, c0, c1, c2, k4x, k4y, k4z);
            sx += H6 * (k1x + 2.0f * k2x + 2.0f * k3x + k4x);
            sy += H6 * (k1y + 2.0f * k2y + 2.0f * k3y + k4y);
            sz += H6 * (k1z + 2.0f * k2z + 2.0f * k3z + k4z);
        };

        unsigned int* wbase = stage + wv * (2 * SLOTW);

        #pragma unroll
        for (int c = 0; c < NCH; ++c) {
            const int len = kLen[c];
            // slot (c&1)'s previous occupant is chunk c-2: wait until flushed
            if (c >= 2) waitGE(&freed[wv], c - 1);
            unsigned int* wb = wbase + (c & 1) * SLOTW + lane * PSTR;
            int u = 0;
            for (int g = 0; g < len / 2; ++g) {
                if (c > 0 || g > 0) step();     // entry 0 is init (no step)
                px = sx; py = sy; pz = sz;
                step();
                wb[u + 0] = bpack(px, py);
                wb[u + 1] = bpack(pz, sx);
                wb[u + 2] = bpack(sy, sz);
                u += 3;
            }
            __threadfence_block();              // drain ds_writes
            if (lane == 0) *(volatile int*)&ready[wv] = c + 1;
        }
    } else {
        // ================= STORER WAVE =================
        // drains all 4 compute waves' chunks in fixed (c, w) order; the only
        // wave issuing global stores -> absorbs all HBM backpressure.
        #pragma unroll
        for (int c = 0; c < NCH; ++c) {
            #pragma unroll
            for (int w = 0; w < 4; ++w) {
                waitGE(&ready[w], c + 1);
                const unsigned int* fb =
                    stage + (w * 2 + (c & 1)) * SLOTW;
                float* __restrict__ outW =
                    out + (blockBase + (long)w * 64) * (3 * NSTEP);
                const int e0 = kOff[c];
                if      (c == 0) flushChunkT< 6>(fb, outW, lane, e0);
                else if (c == 5) flushChunkT< 9>(fb, outW, lane, e0);
                else             flushChunkT<15>(fb, outW, lane, e0);
                __threadfence_block();          // ds_reads of slot complete
                if (lane == 0) *(volatile int*)&freed[w] = c + 1;
            }
        }
    }
}

extern "C" void kernel_launch(void* const* d_in, const int* in_sizes, int n_in,
                              void* d_out, int out_size, void* d_ws, size_t ws_size,
                              hipStream_t stream) {
    const float* features = (const float*)d_in[0];
    const float* W1  = (const float*)d_in[1];
    const float* b1  = (const float*)d_in[2];
    const float* W2  = (const float*)d_in[3];
    const float* b2  = (const float*)d_in[4];
    const float* Wc1 = (const float*)d_in[5];
    const float* bc1 = (const float*)d_in[6];
    const float* Wc2 = (const float*)d_in[7];
    const float* bc2 = (const float*)d_in[8];
    const float* Wp1 = (const float*)d_in[9];
    const float* bp1 = (const float*)d_in[10];
    const float* Wp2 = (const float*)d_in[11];
    const float* bp2 = (const float*)d_in[12];
    float* out = (float*)d_out;

    const int B = in_sizes[0] / 4;          // 262144
    const int grid = B / 256;               // 1024 blocks (256 particles each)

    chaotic_embed_kernel<<<grid, NT, 0, stream>>>(
        features, W1, b1, W2, b2, Wc1, bc1, Wc2, bc2,
        Wp1, bp1, Wp2, bp2, out);
}

// Round 9
// 46.810 us; speedup vs baseline: 1.3147x; 1.3147x over previous
//
#include <hip/hip_runtime.h>

#define NSTEP 50
#define ROWW 75           // packed dwords per particle (150 bf16 = full row)

__device__ __forceinline__ void lorenz(float x, float y, float z,
                                       float S, float R, float Bb,
                                       float c0, float c1, float c2,
                                       float& dx, float& dy, float& dz) {
    dx = S * (y - x) + c0;
    dy = x * (R - z) - y + c1;
    dz = x * y - Bb * z + c2;
}

// pack two f32 -> two bf16 (round-half-up) in one dword; lo in low half
__device__ __forceinline__ unsigned int bpack(float lo, float hi) {
    unsigned int a = (__builtin_bit_cast(unsigned int, lo) + 0x8000u) >> 16;
    unsigned int b = (__builtin_bit_cast(unsigned int, hi) + 0x8000u) & 0xFFFF0000u;
    return a | b;
}
__device__ __forceinline__ float bunpack_lo(unsigned int w) {
    return __builtin_bit_cast(float, w << 16);
}
__device__ __forceinline__ float bunpack_hi(unsigned int w) {
    return __builtin_bit_cast(float, w & 0xFFFF0000u);
}

__device__ __forceinline__ float tanh_fast(float x) {
    float e = __expf(2.0f * x);
    float r = __builtin_amdgcn_rcpf(e + 1.0f);
    return __builtin_fmaf(-2.0f, r, 1.0f);
}
__device__ __forceinline__ float sigmoid_fast(float x) {
    float e = __expf(-x);
    return __builtin_amdgcn_rcpf(1.0f + e);
}

// 1 wave per block, 64 particles, full-row bf16 staging (19.2 KB LDS ->
// 8 blocks/CU). Bulk contiguous flush at end; inter-block pipelining
// overlaps one block's drain with the next block's compute.
__global__ __launch_bounds__(64) void chaotic_embed_kernel(
    const float* __restrict__ features,
    const float* __restrict__ W1,  const float* __restrict__ b1,
    const float* __restrict__ W2,  const float* __restrict__ b2,
    const float* __restrict__ Wc1, const float* __restrict__ bc1,
    const float* __restrict__ Wc2, const float* __restrict__ bc2,
    const float* __restrict__ Wp1, const float* __restrict__ bp1,
    const float* __restrict__ Wp2, const float* __restrict__ bp2,
    float* __restrict__ out)
{
    __shared__ unsigned int img[64 * ROWW];    // linear bf16 image of block's
                                               // contiguous 38400B out region
    const int lane = threadIdx.x;
    const long p = (long)blockIdx.x * 64 + lane;

    const float4 f4 = ((const float4*)features)[p];
    const float fv[4] = {f4.x, f4.y, f4.z, f4.w};

    // ---- MLPs: compile-time weight indices -> uniform s_load, SGPR operands
    float h1[16];
    #pragma unroll
    for (int j = 0; j < 16; ++j) {
        float a = b1[j];
        #pragma unroll
        for (int i = 0; i < 4; ++i) a = __builtin_fmaf(fv[i], W1[i * 16 + j], a);
        h1[j] = tanh_fast(a);
    }
    float init[3];
    #pragma unroll
    for (int c = 0; c < 3; ++c) {
        float a = b2[c];
        #pragma unroll
        for (int j = 0; j < 16; ++j) a = __builtin_fmaf(h1[j], W2[j * 3 + c], a);
        init[c] = 2.0f * tanh_fast(a);
    }
    float hc[8];
    #pragma unroll
    for (int j = 0; j < 8; ++j) {
        float a = bc1[j];
        #pragma unroll
        for (int i = 0; i < 4; ++i) a = __builtin_fmaf(fv[i], Wc1[i * 8 + j], a);
        hc[j] = tanh_fast(a);
    }
    float coup[3];
    #pragma unroll
    for (int c = 0; c < 3; ++c) {
        float a = bc2[c];
        #pragma unroll
        for (int j = 0; j < 8; ++j) a = __builtin_fmaf(hc[j], Wc2[j * 3 + c], a);
        coup[c] = tanh_fast(a);
    }
    float hp[8];
    #pragma unroll
    for (int j = 0; j < 8; ++j) {
        float a = bp1[j];
        #pragma unroll
        for (int i = 0; i < 4; ++i) a = __builtin_fmaf(fv[i], Wp1[i * 8 + j], a);
        hp[j] = fmaxf(a, 0.0f);
    }
    float sc[3];
    #pragma unroll
    for (int c = 0; c < 3; ++c) {
        float a = bp2[c];
        #pragma unroll
        for (int j = 0; j < 8; ++j) a = __builtin_fmaf(hp[j], Wp2[j * 3 + c], a);
        sc[c] = sigmoid_fast(a);
    }
    const float S  = 10.0f * (0.5f + sc[0]);
    const float R  = 28.0f * (0.5f + sc[1]);
    const float Bb = (8.0f / 3.0f) * (0.5f + sc[2]);
    const float c0 = coup[0], c1 = coup[1], c2 = coup[2];
    const float H = 0.01f, HH = 0.5f * 0.01f, H6 = 0.01f / 6.0f;

    float sx = init[0], sy = init[1], sz = init[2];
    float px = sx, py = sy, pz = sz;          // entry 0 = init

    unsigned int* row = img + lane * ROWW;    // stride 75 (mod 32 = 11): no conflicts

    int u = 0;
    #pragma unroll 2
    for (int t = 1; t < NSTEP; ++t) {
        float k1x, k1y, k1z, k2x, k2y, k2z, k3x, k3y, k3z, k4x, k4y, k4z;
        lorenz(sx, sy, sz, S, R, Bb, c0, c1, c2, k1x, k1y, k1z);
        lorenz(sx + HH * k1x, sy + HH * k1y, sz + HH * k1z,
               S, R, Bb, c0, c1, c2, k2x, k2y, k2z);
        lorenz(sx + HH * k2x, sy + HH * k2y, sz + HH * k2z,
               S, R, Bb, c0, c1, c2, k3x, k3y, k3z);
        lorenz(sx + H * k3x, sy + H * k3y, sz + H * k3z,
               S, R, Bb, c0, c1, c2, k4x, k4y, k4z);
        sx += H6 * (k1x + 2.0f * k2x + 2.0f * k3x + k4x);
        sy += H6 * (k1y + 2.0f * k2y + 2.0f * k3y + k4y);
        sz += H6 * (k1z + 2.0f * k2z + 2.0f * k3z + k4z);

        if (t & 1) {                          // pack pair (t-1, t)
            row[u + 0] = bpack(px, py);
            row[u + 1] = bpack(pz, sx);
            row[u + 2] = bpack(sy, sz);
            u += 3;
        } else {
            px = sx; py = sy; pz = sz;
        }
    }

    __syncthreads();   // single wave: cheap; orders ds_writes before reads

    // ---- bulk flush: img (4800 dwords) is the linear bf16 image of the
    // block's contiguous 38400B output region (base 64B-aligned).
    // 2400 uint2 reads -> 2400 float4 stores, every 64B line written once.
    float4* __restrict__ outv = (float4*)(out + (long)blockIdx.x * (64 * 150));
    const uint2* __restrict__ img2 = (const uint2*)img;
    for (int g = lane; g < 2400; g += 64) {
        const uint2 ww = img2[g];
        float4 v;
        v.x = bunpack_lo(ww.x);
        v.y = bunpack_hi(ww.x);
        v.z = bunpack_lo(ww.y);
        v.w = bunpack_hi(ww.y);
        outv[g] = v;
    }
    // stores may remain in flight at endpgm; block slot frees for the next
    // block whose compute phase overlaps this drain.
}

extern "C" void kernel_launch(void* const* d_in, const int* in_sizes, int n_in,
                              void* d_out, int out_size, void* d_ws, size_t ws_size,
                              hipStream_t stream) {
    const float* features = (const float*)d_in[0];
    const float* W1  = (const float*)d_in[1];
    const float* b1  = (const float*)d_in[2];
    const float* W2  = (const float*)d_in[3];
    const float* b2  = (const float*)d_in[4];
    const float* Wc1 = (const float*)d_in[5];
    const float* bc1 = (const float*)d_in[6];
    const float* Wc2 = (const float*)d_in[7];
    const float* bc2 = (const float*)d_in[8];
    const float* Wp1 = (const float*)d_in[9];
    const float* bp1 = (const float*)d_in[10];
    const float* Wp2 = (const float*)d_in[11];
    const float* bp2 = (const float*)d_in[12];
    float* out = (float*)d_out;

    const int B = in_sizes[0] / 4;          // 262144
    const int grid = B / 64;                // 4096 one-wave blocks

    chaotic_embed_kernel<<<grid, 64, 0, stream>>>(
        features, W1, b1, W2, b2, Wc1, bc1, Wc2, bc2,
        Wp1, bp1, Wp2, bp2, out);
}